// Round 1
// baseline (4317.778 us; speedup 1.0000x reference)
//
#include <hip/hip_runtime.h>
#include <hip/hip_cooperative_groups.h>

namespace cg = cooperative_groups;

#define NS    8
#define HGT   128
#define WID   128
#define HW    (HGT * WID)      // 16384
#define BATCH 32
#define EPSV  1e-8f
#define ITERS 20

// full-row tiles: 128 wide x 8 tall, 256 threads x 4 pixels each
#define TH   8
#define LH   (TH + 4)          // 12 rows (halo 2 each side)
#define LW   132               // 128 + 2 halo each side

typedef float4 f4;
typedef _Float16 half4 __attribute__((ext_vector_type(4)));

// ===========================================================================
// Shared helpers (persistent path)
// ===========================================================================
__device__ __forceinline__ void stage_tile(const float* __restrict__ m_in,
                                           int b, int ty0, int tid,
                                           float tile[NS][LH][LW]) {
#pragma unroll
    for (int c = 0; c < NS; ++c) {
        const float* src = m_in + (b * NS + c) * HW;
        for (int t = tid; t < LH * 32; t += 256) {
            int ly = t >> 5, lxq = t & 31;
            int gh = (ty0 + ly - 2 + HGT) & (HGT - 1);
            f4 val = *(const f4*)(src + gh * WID + lxq * 4);
            float* dst = &tile[c][ly][2 + lxq * 4];
            dst[0] = val.x; dst[1] = val.y; dst[2] = val.z; dst[3] = val.w;
        }
        // edge columns: hx 0,1 <- x 126,127 ; hx 130,131 <- x 0,1
        if (tid < LH * 4) {
            int ly = tid >> 2, e = tid & 3;
            int gh = (ty0 + ly - 2 + HGT) & (HGT - 1);
            int x  = (e < 2) ? (126 + e) : (e - 2);
            int hx = (e < 2) ? e : (128 + e);
            tile[c][ly][hx] = src[gh * WID + x];
        }
    }
}

__device__ __forceinline__ f4 conv5(const float (*tc)[LW], const float* wk,
                                    int ly, int lxq) {
    float s0 = 0.f, s1 = 0.f, s2 = 0.f, s3 = 0.f;
#pragma unroll
    for (int dy = 0; dy < 5; ++dy) {
        const float* row = &tc[ly + dy][lxq * 4];   // 16B aligned
        f4 A = *(const f4*)row;
        f4 B = *(const f4*)(row + 4);
        float vv[8] = {A.x, A.y, A.z, A.w, B.x, B.y, B.z, B.w};
#pragma unroll
        for (int dx = 0; dx < 5; ++dx) {
            float w = wk[dy * 5 + dx];
            s0 += w * vv[dx];
            s1 += w * vv[dx + 1];
            s2 += w * vv[dx + 2];
            s3 += w * vv[dx + 3];
        }
    }
    return f4{s0, s1, s2, s3};
}

// ===========================================================================
// Persistent cooperative kernel: init + 20 Sinkhorn iterations + epilogue.
// u,v live in registers; only mrow/mcol (halo exchange) and H0h (fp16 matrix,
// block-private pixels) touch global memory inside the loop.
// 512 blocks (16 y-tiles x 32 batches), 2 blocks/CU, grid.sync per half-step.
// ===========================================================================
__global__ __launch_bounds__(256, 2) void k_sink_all(
        const float* __restrict__ logH, _Float16* __restrict__ H0h,
        float* __restrict__ mrow, float* __restrict__ mcol,
        const float* __restrict__ gk, float* __restrict__ out) {
    cg::grid_group grid = cg::this_grid();
    __shared__ float tile[NS][LH][LW];
    __shared__ float wk[25];
    int tid = threadIdx.x;
    int ty0 = blockIdx.x * TH;
    int b   = blockIdx.y;
    if (tid < 25) wk[tid] = gk[tid];

    int lxq = tid & 31;
    int ly  = tid >> 5;
    int p   = (ty0 + ly) * WID + lxq * 4;

    const float* Lb = logH + (b * NS * NS) * HW + p;
    _Float16*    Hb = H0h  + (b * NS * NS) * HW + p;

    f4 u[NS], v[NS];

    // ---- init: H0h = fp16(exp(logH)) (block-private pixels, no sync needed),
    //            mrow[b,i,p] = sum_j exp(logH)  (u=v=1)
#pragma unroll
    for (int i = 0; i < NS; ++i) {
        f4 si = {0.f, 0.f, 0.f, 0.f};
#pragma unroll
        for (int j = 0; j < NS; ++j) {
            f4 l = *(const f4*)(Lb + (i * NS + j) * HW);
            f4 ev;
            ev.x = __expf(l.x); ev.y = __expf(l.y);
            ev.z = __expf(l.z); ev.w = __expf(l.w);
            half4 h;
            h.x = (_Float16)ev.x; h.y = (_Float16)ev.y;
            h.z = (_Float16)ev.z; h.w = (_Float16)ev.w;
            *(half4*)(Hb + (i * NS + j) * HW) = h;
            si.x += ev.x; si.y += ev.y; si.z += ev.z; si.w += ev.w;
        }
        *(f4*)(mrow + (b * NS + i) * HW + p) = si;
        u[i] = f4{1.f, 1.f, 1.f, 1.f};
        v[i] = f4{1.f, 1.f, 1.f, 1.f};
    }
    grid.sync();

    for (int it = 0; it < ITERS; ++it) {
        // -------- row step: u /= smooth(mrow)+eps; emit mcol = v .* (M^T u)
        stage_tile(mrow, b, ty0, tid, tile);
        __syncthreads();
#pragma unroll
        for (int c = 0; c < NS; ++c) {
            f4 s = conv5(tile[c], wk, ly, lxq);
            u[c].x /= (s.x + EPSV);
            u[c].y /= (s.y + EPSV);
            u[c].z /= (s.z + EPSV);
            u[c].w /= (s.w + EPSV);
        }
        {
            f4 acc[NS];
#pragma unroll
            for (int cp = 0; cp < NS; ++cp) acc[cp] = f4{0.f, 0.f, 0.f, 0.f};
#pragma unroll
            for (int c = 0; c < NS; ++c) {
                f4 x = u[c];
#pragma unroll
                for (int cp = 0; cp < NS; ++cp) {
                    half4 h = *(const half4*)(Hb + (c * NS + cp) * HW);
                    acc[cp].x += (float)h.x * x.x;
                    acc[cp].y += (float)h.y * x.y;
                    acc[cp].z += (float)h.z * x.z;
                    acc[cp].w += (float)h.w * x.w;
                }
            }
#pragma unroll
            for (int cp = 0; cp < NS; ++cp) {
                f4 o;
                o.x = v[cp].x * acc[cp].x;
                o.y = v[cp].y * acc[cp].y;
                o.z = v[cp].z * acc[cp].z;
                o.w = v[cp].w * acc[cp].w;
                *(f4*)(mcol + (b * NS + cp) * HW + p) = o;
            }
        }
        grid.sync();

        // -------- col step: v /= smooth(mcol)+eps; emit mrow = u .* (M v)
        stage_tile(mcol, b, ty0, tid, tile);
        __syncthreads();
#pragma unroll
        for (int c = 0; c < NS; ++c) {
            f4 s = conv5(tile[c], wk, ly, lxq);
            v[c].x /= (s.x + EPSV);
            v[c].y /= (s.y + EPSV);
            v[c].z /= (s.z + EPSV);
            v[c].w /= (s.w + EPSV);
        }
        if (it != ITERS - 1) {
            f4 acc[NS];
#pragma unroll
            for (int cp = 0; cp < NS; ++cp) acc[cp] = f4{0.f, 0.f, 0.f, 0.f};
#pragma unroll
            for (int c = 0; c < NS; ++c) {
                f4 x = v[c];
#pragma unroll
                for (int cp = 0; cp < NS; ++cp) {
                    half4 h = *(const half4*)(Hb + (cp * NS + c) * HW);
                    acc[cp].x += (float)h.x * x.x;
                    acc[cp].y += (float)h.y * x.y;
                    acc[cp].z += (float)h.z * x.z;
                    acc[cp].w += (float)h.w * x.w;
                }
            }
#pragma unroll
            for (int cp = 0; cp < NS; ++cp) {
                f4 o;
                o.x = u[cp].x * acc[cp].x;
                o.y = u[cp].y * acc[cp].y;
                o.z = u[cp].z * acc[cp].z;
                o.w = u[cp].w * acc[cp].w;
                *(f4*)(mrow + (b * NS + cp) * HW + p) = o;
            }
            grid.sync();
        }
        // last col step: v update only; epilogue below. No H0h reads occur
        // after the final grid.sync, so out-writes may clobber the H0h
        // scratch aliased at the front of d_out.
    }

    // ---- epilogue: out = exp(logH) * u[i] * v[j] + eps  (fp32 recompute)
    float* Ob = out + (b * NS * NS) * HW + p;
#pragma unroll
    for (int i = 0; i < NS; ++i) {
#pragma unroll
        for (int j = 0; j < NS; ++j) {
            f4 l = *(const f4*)(Lb + (i * NS + j) * HW);
            f4 o;
            o.x = expf(l.x) * u[i].x * v[j].x + EPSV;
            o.y = expf(l.y) * u[i].y * v[j].y + EPSV;
            o.z = expf(l.z) * u[i].z * v[j].z + EPSV;
            o.w = expf(l.w) * u[i].w * v[j].w + EPSV;
            *(f4*)(Ob + (i * NS + j) * HW) = o;
        }
    }
}

// ===========================================================================
// Legacy fallback path (proven 41-dispatch version) — used only if the
// cooperative launch is refused.
// ===========================================================================
__global__ __launch_bounds__(256) void k_init(const float* __restrict__ logH,
                                              _Float16* __restrict__ H0h,
                                              float* __restrict__ u,
                                              float* __restrict__ v,
                                              float* __restrict__ mrow) {
    int gid = blockIdx.x * 256 + threadIdx.x;
    int e = gid * 4;
    int p = e & (HW - 1);
    int c = (e >> 14) & 7;
    int b = e >> 17;
    int base = ((b * NS + c) * NS) * HW + p;
    f4 s = {0.f, 0.f, 0.f, 0.f};
#pragma unroll
    for (int j = 0; j < NS; ++j) {
        f4 l = *(const f4*)(logH + base + j * HW);
        f4 ev;
        ev.x = __expf(l.x); ev.y = __expf(l.y);
        ev.z = __expf(l.z); ev.w = __expf(l.w);
        half4 h;
        h.x = (_Float16)ev.x; h.y = (_Float16)ev.y;
        h.z = (_Float16)ev.z; h.w = (_Float16)ev.w;
        *(half4*)(H0h + base + j * HW) = h;
        s.x += ev.x; s.y += ev.y; s.z += ev.z; s.w += ev.w;
    }
    f4 one = {1.f, 1.f, 1.f, 1.f};
    *(f4*)(u + e) = one;
    *(f4*)(v + e) = one;
    *(f4*)(mrow + e) = s;
}

__device__ __forceinline__ void stage_and_smooth(
        const float* __restrict__ m_in, const float* __restrict__ gk,
        float* __restrict__ a, int b, int ty0, int tid,
        float tile[NS][LH][LW], float wk[25], f4 av[NS], bool write_a) {
    if (tid < 25) wk[tid] = gk[tid];
    stage_tile(m_in, b, ty0, tid, tile);
    __syncthreads();

    int lxq = tid & 31;
    int ly  = tid >> 5;
    int p   = (ty0 + ly) * WID + lxq * 4;

#pragma unroll
    for (int c = 0; c < NS; ++c) {
        f4 s = conv5(tile[c], wk, ly, lxq);
        int ai = (b * NS + c) * HW + p;
        f4 ao = *(const f4*)(a + ai);
        f4 un;
        un.x = ao.x / (s.x + EPSV);
        un.y = ao.y / (s.y + EPSV);
        un.z = ao.z / (s.z + EPSV);
        un.w = ao.w / (s.w + EPSV);
        if (write_a) *(f4*)(a + ai) = un;
        av[c] = un;
    }
}

template <int ROWSTEP>
__global__ __launch_bounds__(256) void k_step(const float* __restrict__ m_in,
                                              float* __restrict__ a,
                                              const float* __restrict__ bvec,
                                              float* __restrict__ m_out,
                                              const _Float16* __restrict__ H0h,
                                              const float* __restrict__ gk) {
    __shared__ float tile[NS][LH][LW];
    __shared__ float wk[25];
    int tid = threadIdx.x;
    int b   = blockIdx.z;
    int ty0 = blockIdx.y * TH;

    f4 av[NS];
    stage_and_smooth(m_in, gk, a, b, ty0, tid, tile, wk, av, true);

    int lxq = tid & 31;
    int ly  = tid >> 5;
    int p   = (ty0 + ly) * WID + lxq * 4;

    f4 acc[NS];
#pragma unroll
    for (int cp = 0; cp < NS; ++cp) acc[cp] = f4{0.f, 0.f, 0.f, 0.f};
    const _Float16* Hb = H0h + b * NS * NS * HW + p;
#pragma unroll
    for (int c = 0; c < NS; ++c) {
        f4 x = av[c];
#pragma unroll
        for (int cp = 0; cp < NS; ++cp) {
            int ch = ROWSTEP ? (c * NS + cp) : (cp * NS + c);
            half4 h = *(const half4*)(Hb + ch * HW);
            acc[cp].x += (float)h.x * x.x;
            acc[cp].y += (float)h.y * x.y;
            acc[cp].z += (float)h.z * x.z;
            acc[cp].w += (float)h.w * x.w;
        }
    }
#pragma unroll
    for (int cp = 0; cp < NS; ++cp) {
        int oi = (b * NS + cp) * HW + p;
        f4 bv = *(const f4*)(bvec + oi);
        f4 o;
        o.x = bv.x * acc[cp].x;
        o.y = bv.y * acc[cp].y;
        o.z = bv.z * acc[cp].z;
        o.w = bv.w * acc[cp].w;
        *(f4*)(m_out + oi) = o;
    }
}

__global__ __launch_bounds__(256) void k_last(const float* __restrict__ m_in,
                                              float* __restrict__ v,
                                              const float* __restrict__ u,
                                              const float* __restrict__ logH,
                                              float* __restrict__ out,
                                              const float* __restrict__ gk) {
    __shared__ float tile[NS][LH][LW];
    __shared__ float wk[25];
    int tid = threadIdx.x;
    int b   = blockIdx.z;
    int ty0 = blockIdx.y * TH;

    f4 av[NS];
    stage_and_smooth(m_in, gk, v, b, ty0, tid, tile, wk, av, false);

    int lxq = tid & 31;
    int ly  = tid >> 5;
    int p   = (ty0 + ly) * WID + lxq * 4;

    const float* Lb = logH + b * NS * NS * HW + p;
    float* Ob = out + b * NS * NS * HW + p;
#pragma unroll
    for (int i = 0; i < NS; ++i) {
        f4 uu = *(const f4*)(u + (b * NS + i) * HW + p);
#pragma unroll
        for (int j = 0; j < NS; ++j) {
            f4 l = *(const f4*)(Lb + (i * NS + j) * HW);
            f4 o;
            o.x = expf(l.x) * uu.x * av[j].x + EPSV;
            o.y = expf(l.y) * uu.y * av[j].y + EPSV;
            o.z = expf(l.z) * uu.z * av[j].z + EPSV;
            o.w = expf(l.w) * uu.w * av[j].w + EPSV;
            *(f4*)(Ob + (i * NS + j) * HW) = o;
        }
    }
}

// ===========================================================================
extern "C" void kernel_launch(void* const* d_in, const int* in_sizes, int n_in,
                              void* d_out, int out_size, void* d_ws, size_t ws_size,
                              hipStream_t stream) {
    const float* logH = (const float*)d_in[0];
    const float* gk   = (const float*)d_in[1];
    float* out = (float*)d_out;                 // final output; front half doubles as H0h scratch
    _Float16* H0h = (_Float16*)d_out;           // 67 MB fp16 scratch inside d_out
    float* ws = (float*)d_ws;
    const int VEC = BATCH * NS * HW;            // 4,194,304 floats per marginal set

    // ---- persistent cooperative path: 1 dispatch, u/v in registers ----
    float* mrow = ws;
    float* mcol = ws + VEC;                     // d_ws usage: 33.5 MB
    void* args[] = {(void*)&logH, (void*)&H0h, (void*)&mrow, (void*)&mcol,
                    (void*)&gk, (void*)&out};
    hipError_t err = hipLaunchCooperativeKernel(k_sink_all,
                                                dim3(HGT / TH, BATCH, 1),
                                                dim3(256, 1, 1),
                                                args, 0, stream);
    if (err == hipSuccess) return;

    // ---- fallback: proven 41-dispatch path ----
    float* u     = ws;
    float* v     = ws + VEC;
    float* mrow2 = ws + 2 * (size_t)VEC;
    float* mcol2 = ws + 3 * (size_t)VEC;        // d_ws usage: 67 MB

    k_init<<<VEC / 4 / 256, 256, 0, stream>>>(logH, H0h, u, v, mrow2);

    dim3 grid(1, HGT / TH, BATCH);
    for (int it = 0; it < ITERS; ++it) {
        k_step<1><<<grid, 256, 0, stream>>>(mrow2, u, v, mcol2, H0h, gk);
        if (it != ITERS - 1) {
            k_step<0><<<grid, 256, 0, stream>>>(mcol2, v, u, mrow2, H0h, gk);
        } else {
            k_last<<<grid, 256, 0, stream>>>(mcol2, v, u, logH, out, gk);
        }
    }
}

// Round 4
// 1361.443 us; speedup vs baseline: 3.1715x; 3.1715x over previous
//
#include <hip/hip_runtime.h>

#define NS    8
#define HGT   128
#define WID   128
#define HW    (HGT * WID)      // 16384
#define BATCH 32
#define EPSV  1e-8f
#define ITERS 20

// full-row tiles: 128 wide x 8 tall; 512 threads x 2 pixels each
#define TH   8
#define LH   (TH + 4)          // 12 rows (halo 2 each side)
#define LW   132               // 128 + 2 halo each side

typedef float4 f4;
typedef float2 f2;
typedef _Float16 half4 __attribute__((ext_vector_type(4)));
typedef _Float16 half2v __attribute__((ext_vector_type(2)));

// ---------------------------------------------------------------------------
// Prologue: H0h = fp16(exp(logH)) (into d_out as scratch),
// mrow[b,i,p] = sum_j exp(logH)[b,i,j,p]  (u=v=1 initially; u,v buffers are
// NOT initialized — the FIRST-specialized steps below never read them).
__global__ __launch_bounds__(256) void k_init(const float* __restrict__ logH,
                                              _Float16* __restrict__ H0h,
                                              float* __restrict__ mrow) {
    int gid = blockIdx.x * 256 + threadIdx.x;   // over VEC/4 = 1,048,576
    int e = gid * 4;
    int p = e & (HW - 1);
    int c = (e >> 14) & 7;
    int b = e >> 17;
    int base = ((b * NS + c) * NS) * HW + p;
    f4 s = {0.f, 0.f, 0.f, 0.f};
#pragma unroll
    for (int j = 0; j < NS; ++j) {
        f4 l = *(const f4*)(logH + base + j * HW);
        f4 ev;
        ev.x = __expf(l.x); ev.y = __expf(l.y);
        ev.z = __expf(l.z); ev.w = __expf(l.w);
        half4 h;
        h.x = (_Float16)ev.x; h.y = (_Float16)ev.y;
        h.z = (_Float16)ev.z; h.w = (_Float16)ev.w;
        *(half4*)(H0h + base + j * HW) = h;
        s.x += ev.x; s.y += ev.y; s.z += ev.z; s.w += ev.w;
    }
    *(f4*)(mrow + e) = s;
}

// ---------------------------------------------------------------------------
// Stage 8-channel tile of m_in (12 rows x 132 cols, circular) into LDS.
// 512 threads: tid<384 stage the body (f4), last 48 threads do edge cols.
__device__ __forceinline__ void stage_tile(const float* __restrict__ m_in,
                                           int b, int ty0, int tid,
                                           float tile[NS][LH][LW]) {
#pragma unroll
    for (int c = 0; c < NS; ++c) {
        const float* src = m_in + (b * NS + c) * HW;
        if (tid < LH * 32) {                    // 384 threads: 12 rows x 32 f4
            int ly = tid >> 5, lxq = tid & 31;
            int gh = (ty0 + ly - 2 + HGT) & (HGT - 1);
            f4 val = *(const f4*)(src + gh * WID + lxq * 4);
            float* dst = &tile[c][ly][2 + lxq * 4];
            dst[0] = val.x; dst[1] = val.y; dst[2] = val.z; dst[3] = val.w;
        } else if (tid >= 512 - LH * 4) {       // 48 threads: edge columns
            int t = tid - (512 - LH * 4);
            int ly = t >> 2, e = t & 3;
            int gh = (ty0 + ly - 2 + HGT) & (HGT - 1);
            int x  = (e < 2) ? (126 + e) : (e - 2);
            int hx = (e < 2) ? e : (128 + e);
            tile[c][ly][hx] = src[gh * WID + x];
        }
    }
}

// 5x5 conv for a thread's 2 adjacent pixels (float2 granule).
__device__ __forceinline__ f2 conv5(const float (*tc)[LW], const float* wk,
                                    int ly, int lx2) {
    float s0 = 0.f, s1 = 0.f;
#pragma unroll
    for (int dy = 0; dy < 5; ++dy) {
        const float* row = &tc[ly + dy][lx2 * 2];   // 8B aligned, 6 floats
        f2 A = *(const f2*)row;
        f2 B = *(const f2*)(row + 2);
        f2 C = *(const f2*)(row + 4);
        float vv[6] = {A.x, A.y, B.x, B.y, C.x, C.y};
#pragma unroll
        for (int dx = 0; dx < 5; ++dx) {
            float w = wk[dy * 5 + dx];
            s0 += w * vv[dx];
            s1 += w * vv[dx + 1];
        }
    }
    return f2{s0, s1};
}

// ---------------------------------------------------------------------------
// One Sinkhorn half-step: a /= (smooth(m_in)+eps); emit the other marginal
// m_out[c'] = bvec[c'] * sum_c H0h[sel] * a[c]   (H0h in fp16).
// ROWSTEP=1: a=u, emit over j (ch c*8+cp). ROWSTEP=0: a=v (ch cp*8+c).
// FIRST=1: a==1 on input (skip read); additionally bvec==1 when ROWSTEP=1.
template <int ROWSTEP, int FIRST>
__global__ __launch_bounds__(512, 4) void k_step(const float* __restrict__ m_in,
                                                 float* __restrict__ a,
                                                 const float* __restrict__ bvec,
                                                 float* __restrict__ m_out,
                                                 const _Float16* __restrict__ H0h,
                                                 const float* __restrict__ gk) {
    __shared__ float tile[NS][LH][LW];
    __shared__ float wk[25];
    int tid = threadIdx.x;
    int b   = blockIdx.z;
    int ty0 = blockIdx.y * TH;
    if (tid < 25) wk[tid] = gk[tid];

    stage_tile(m_in, b, ty0, tid, tile);
    __syncthreads();

    int lx2 = tid & 63;            // float2 column index 0..63
    int ly  = tid >> 6;            // 0..7
    int p   = (ty0 + ly) * WID + lx2 * 2;

    f2 av[NS];
#pragma unroll
    for (int c = 0; c < NS; ++c) {
        f2 s = conv5(tile[c], wk, ly, lx2);
        int ai = (b * NS + c) * HW + p;
        f2 un;
        if (FIRST) {
            un.x = 1.f / (s.x + EPSV);
            un.y = 1.f / (s.y + EPSV);
        } else {
            f2 ao = *(const f2*)(a + ai);
            un.x = ao.x / (s.x + EPSV);
            un.y = ao.y / (s.y + EPSV);
        }
        *(f2*)(a + ai) = un;
        av[c] = un;
    }

    f2 acc[NS];
#pragma unroll
    for (int cp = 0; cp < NS; ++cp) acc[cp] = f2{0.f, 0.f};
    const _Float16* Hb = H0h + b * NS * NS * HW + p;
#pragma unroll
    for (int c = 0; c < NS; ++c) {
        f2 x = av[c];
#pragma unroll
        for (int cp = 0; cp < NS; ++cp) {
            int ch = ROWSTEP ? (c * NS + cp) : (cp * NS + c);
            half2v h = *(const half2v*)(Hb + ch * HW);
            acc[cp].x += (float)h.x * x.x;
            acc[cp].y += (float)h.y * x.y;
        }
    }
#pragma unroll
    for (int cp = 0; cp < NS; ++cp) {
        int oi = (b * NS + cp) * HW + p;
        f2 o;
        if (ROWSTEP && FIRST) {        // bvec == 1
            o = acc[cp];
        } else {
            f2 bv = *(const f2*)(bvec + oi);
            o.x = bv.x * acc[cp].x;
            o.y = bv.y * acc[cp].y;
        }
        *(f2*)(m_out + oi) = o;
    }
}

// ---------------------------------------------------------------------------
// Last col-step fused with epilogue: vnew = v/(smooth(mcol)+eps) (not stored),
// out[b,i,j,p] = exp(logH)[b,i,j,p] * u[b,i,p] * vnew[b,j,p] + eps.
// Recomputes exp from pristine logH in full fp32 (overwrites the fp16 H0h
// scratch living in d_out — never read here, so no hazard).
__global__ __launch_bounds__(512, 4) void k_last(const float* __restrict__ m_in,
                                                 const float* __restrict__ v,
                                                 const float* __restrict__ u,
                                                 const float* __restrict__ logH,
                                                 float* __restrict__ out,
                                                 const float* __restrict__ gk) {
    __shared__ float tile[NS][LH][LW];
    __shared__ float wk[25];
    int tid = threadIdx.x;
    int b   = blockIdx.z;
    int ty0 = blockIdx.y * TH;
    if (tid < 25) wk[tid] = gk[tid];

    stage_tile(m_in, b, ty0, tid, tile);
    __syncthreads();

    int lx2 = tid & 63;
    int ly  = tid >> 6;
    int p   = (ty0 + ly) * WID + lx2 * 2;

    f2 av[NS];                         // vnew[j]
#pragma unroll
    for (int c = 0; c < NS; ++c) {
        f2 s = conv5(tile[c], wk, ly, lx2);
        f2 vo = *(const f2*)(v + (b * NS + c) * HW + p);
        av[c].x = vo.x / (s.x + EPSV);
        av[c].y = vo.y / (s.y + EPSV);
    }

    const float* Lb = logH + b * NS * NS * HW + p;
    float* Ob = out + b * NS * NS * HW + p;
#pragma unroll
    for (int i = 0; i < NS; ++i) {
        f2 uu = *(const f2*)(u + (b * NS + i) * HW + p);
#pragma unroll
        for (int j = 0; j < NS; ++j) {
            f2 l = *(const f2*)(Lb + (i * NS + j) * HW);
            f2 o;
            o.x = expf(l.x) * uu.x * av[j].x + EPSV;
            o.y = expf(l.y) * uu.y * av[j].y + EPSV;
            *(f2*)(Ob + (i * NS + j) * HW) = o;
        }
    }
}

// ===========================================================================
extern "C" void kernel_launch(void* const* d_in, const int* in_sizes, int n_in,
                              void* d_out, int out_size, void* d_ws, size_t ws_size,
                              hipStream_t stream) {
    const float* logH = (const float*)d_in[0];
    const float* gk   = (const float*)d_in[1];
    float* out = (float*)d_out;                 // final output; front doubles as H0h scratch
    _Float16* H0h = (_Float16*)d_out;           // 67 MB fp16 scratch inside d_out
    float* ws = (float*)d_ws;
    const int VEC = BATCH * NS * HW;            // 4,194,304
    float* u    = ws;
    float* v    = ws + VEC;
    float* mrow = ws + 2 * (size_t)VEC;
    float* mcol = ws + 3 * (size_t)VEC;         // d_ws usage: 67 MB

    k_init<<<VEC / 4 / 256, 256, 0, stream>>>(logH, H0h, mrow);

    dim3 grid(1, HGT / TH, BATCH);              // 512 blocks x 512 threads
    // it = 0: u,v start at 1 — specialized variants skip those reads
    k_step<1, 1><<<grid, 512, 0, stream>>>(mrow, u, v, mcol, H0h, gk);
    k_step<0, 1><<<grid, 512, 0, stream>>>(mcol, v, u, mrow, H0h, gk);
    for (int it = 1; it < ITERS; ++it) {
        // row step: u /= smooth(mrow)+eps; emit mcol = v .* (M^T u)
        k_step<1, 0><<<grid, 512, 0, stream>>>(mrow, u, v, mcol, H0h, gk);
        if (it != ITERS - 1) {
            // col step: v /= smooth(mcol)+eps; emit mrow = u .* (M v)
            k_step<0, 0><<<grid, 512, 0, stream>>>(mcol, v, u, mrow, H0h, gk);
        } else {
            // fused last col step + epilogue (fp32 exp recompute, final write)
            k_last<<<grid, 512, 0, stream>>>(mcol, v, u, logH, out, gk);
        }
    }
}